// Round 9
// baseline (341.448 us; speedup 1.0000x reference)
//
#include <hip/hip_runtime.h>
#include <math.h>

// Problem constants: B=1, CIN=COUT=32, KS=3 (K=27), D=32, H=W=64, stride=1, pad=1, dil=1
#define DD 32
#define HH 64
#define WW 64
#define CSTRIDE (DD * HH * WW)   // 131072
#define NPOS (DD * HH * WW)

// sample_einsum slab geometry: per-block LDS tile of xT covering all likely
// sample corners for 16 output cols (offset std ~0.3 => +-2 margin).
#define SLAB_Z 5
#define SLAB_Y 5
#define SLAB_X 20
#define SLAB_POS (SLAB_Z * SLAB_Y * SLAB_X)   // 500 positions = 32,000 B

typedef __attribute__((ext_vector_type(8))) short  short8;      // 16B load vehicle
typedef _Float16 __attribute__((ext_vector_type(8))) half8;     // 8 fp16 MFMA A/B frag
typedef __attribute__((ext_vector_type(4))) float  float4v;     // MFMA C/D frag
typedef __attribute__((ext_vector_type(2))) float  f2v;
typedef __attribute__((ext_vector_type(4))) unsigned int uint4v;
typedef __attribute__((ext_vector_type(2))) unsigned int uint2v;

__device__ __forceinline__ unsigned short f2h(float f) {
    return __builtin_bit_cast(unsigned short, (_Float16)f);
}
__device__ __forceinline__ float h2f(unsigned short u) {
    return (float)__builtin_bit_cast(_Float16, u);
}
__device__ __forceinline__ unsigned pkh(float a, float b) {
    return (unsigned)f2h(a) | ((unsigned)f2h(b) << 16);
}
__device__ __forceinline__ float4v mfma16(half8 a, half8 b, float4v c) {
    return __builtin_amdgcn_mfma_f32_16x16x32_f16(a, b, c, 0, 0, 0);
}

// ---------------------------------------------------------------------------
// prep_all: fused prep_x + prep_w — unchanged from r8 (fp16 pipeline).
// ---------------------------------------------------------------------------
__global__ __launch_bounds__(256) void prep_all(
    const float* __restrict__ x, unsigned short* __restrict__ xT,
    const float* __restrict__ w_off, const float* __restrict__ w_mask,
    const float* __restrict__ w,
    unsigned short* __restrict__ wAc, unsigned short* __restrict__ wAe)
{
    if (blockIdx.x < NPOS / 256) {
        int pos = blockIdx.x * 256 + threadIdx.x;
        float v[32];
#pragma unroll
        for (int ci = 0; ci < 32; ci++) v[ci] = x[ci * CSTRIDE + pos];
        unsigned dw[16];
#pragma unroll
        for (int p = 0; p < 16; p++)
            dw[p] = (unsigned)f2h(v[2 * p]) | ((unsigned)f2h(v[2 * p + 1]) << 16);
        uint4v* dst = (uint4v*)(xT + (size_t)pos * 32);
#pragma unroll
        for (int o = 0; o < 4; o++) {
            uint4v t4 = {dw[4 * o], dw[4 * o + 1], dw[4 * o + 2], dw[4 * o + 3]};
            dst[o] = t4;
        }
    } else {
        int i = (blockIdx.x - NPOS / 256) * 256 + threadIdx.x;
        if (i < 27 * 7 * 64 * 8) {                       // 96768: conv A-frags
            int j    = i & 7;
            int lane = (i >> 3) & 63;
            int fm   = i >> 9;
            int mt   = fm % 7;
            int tapw = fm / 7;                           // conv kernel tap
            int ch   = mt * 16 + (lane & 15);            // ch' = tap_o*4+comp
            int ci   = (lane >> 4) * 8 + j;
            float v = 0.f;
            if (ch < 108) {
                int tapo = ch >> 2, comp = ch & 3;
                v = (comp < 3) ? w_off[((comp * 27 + tapo) * 32 + ci) * 27 + tapw]
                               : w_mask[(tapo * 32 + ci) * 27 + tapw];
            }
            wAc[i] = f2h(v);
        } else {                                         // 27648: einsum A-frags
            int i2   = i - 27 * 7 * 64 * 8;
            int j    = i2 & 7;
            int lane = (i2 >> 3) & 63;
            int fm   = i2 >> 9;
            int mt   = fm % 2;
            int tapw = fm / 2;
            int co   = mt * 16 + (lane & 15);
            int ci   = (lane >> 4) * 8 + j;
            wAe[i2] = f2h(w[(co * 32 + ci) * 27 + tapw]);
        }
    }
}

// ---------------------------------------------------------------------------
// conv_offm v7b: unchanged from r8 (passing version).
// ---------------------------------------------------------------------------
__global__ __launch_bounds__(256, 4) void conv_offm(
    const unsigned short* __restrict__ xT,
    const unsigned short* __restrict__ wAc,
    const float* __restrict__ b_off, const float* __restrict__ b_mask,
    unsigned int* __restrict__ offmH)
{
    __shared__ __align__(16) unsigned short sA[2][3584];   // 2 x 7168 B

    int bid = blockIdx.x;
    int swz = (bid & 7) * 128 + (bid >> 3);        // 8 XCD chunks of 128
    const int t = threadIdx.x, lane = t & 63;
    const int wv = t >> 6, wl = lane & 15, q = lane >> 4;
    const int row = swz * 2 + (wv >> 1);
    const int z = row >> 6, y = row & 63;
    const int xb = (wv & 1) * 32;

    {
        uint4v v0a = *(const uint4v*)(wAc + (size_t)t * 8);
        uint4v v1a = *(const uint4v*)(wAc + 3584 + (size_t)t * 8);
        uint4v v0b, v1b;
        if (t < 192) {
            v0b = *(const uint4v*)(wAc + (size_t)(256 + t) * 8);
            v1b = *(const uint4v*)(wAc + 3584 + (size_t)(256 + t) * 8);
        }
        *(uint4v*)(&sA[0][0] + t * 8) = v0a;
        *(uint4v*)(&sA[1][0] + t * 8) = v1a;
        if (t < 192) {
            *(uint4v*)(&sA[0][0] + (256 + t) * 8) = v0b;
            *(uint4v*)(&sA[1][0] + (256 + t) * 8) = v1b;
        }
    }
    __syncthreads();

    float4v acc[7][2];
#pragma unroll
    for (int mt = 0; mt < 7; mt++)
#pragma unroll
        for (int nt = 0; nt < 2; nt++)
            acc[mt][nt] = (float4v){0.f, 0.f, 0.f, 0.f};

    for (int tap = 0; tap < 27; tap++) {
        const int p  = tap & 1;
        const int kz = tap / 9, r9 = tap - kz * 9;
        const int ky = r9 / 3,  kx = r9 - ky * 3;

        int zs = z + kz - 1;
        bool zok = (unsigned)zs < (unsigned)DD;
        int zc = min(max(zs, 0), DD - 1);
        int ys = y + ky - 1;
        bool yok = (unsigned)ys < (unsigned)HH;
        int yc = min(max(ys, 0), HH - 1);
        int rowp = (zc * HH + yc) * WW;

        short8 b0, b1;
#pragma unroll
        for (int nt = 0; nt < 2; nt++) {
            int xs = xb + nt * 16 + wl + kx - 1;
            bool ok = zok & yok & ((unsigned)xs < (unsigned)WW);
            int xc = min(max(xs, 0), WW - 1);
            short8 bb = *(const short8*)(xT + (size_t)(rowp + xc) * 32 + q * 8);
            if (!ok) bb = (short8)0;
            if (nt == 0) b0 = bb; else b1 = bb;
        }

        uint4v sva, svb;
        bool pre = (tap + 2 < 27);
        if (pre) {
            const unsigned short* src = wAc + (size_t)(tap + 2) * 3584;
            sva = *(const uint4v*)(src + (size_t)t * 8);
            if (t < 192) svb = *(const uint4v*)(src + (size_t)(256 + t) * 8);
        }

        const unsigned short* sAp = &sA[p][0] + lane * 8;
#pragma unroll
        for (int mt = 0; mt < 7; mt++) {
            half8 a = __builtin_bit_cast(half8, *(const short8*)(sAp + mt * 512));
            acc[mt][0] = mfma16(a, __builtin_bit_cast(half8, b0), acc[mt][0]);
            acc[mt][1] = mfma16(a, __builtin_bit_cast(half8, b1), acc[mt][1]);
        }

        __syncthreads();
        if (pre) {
            *(uint4v*)(&sA[p][0] + t * 8) = sva;
            if (t < 192) *(uint4v*)(&sA[p][0] + (256 + t) * 8) = svb;
        }
    }

    const int rowpos = row * WW;
#pragma unroll
    for (int mt = 0; mt < 7; mt++) {
        int tapo = mt * 4 + q;
        if (tapo < 27) {
            float bz = b_off[tapo], by = b_off[27 + tapo], bx = b_off[54 + tapo];
            float bm = b_mask[tapo];
#pragma unroll
            for (int nt = 0; nt < 2; nt++) {
                float4v v = acc[mt][nt];
                float mm = v.w + bm;
                mm = 1.f / (1.f + __expf(-mm));
                int posn = rowpos + xb + nt * 16 + wl;
                uint2v pk = { pkh(v.x + bz, v.y + by), pkh(v.z + bx, mm) };
                *(uint2v*)(offmH + ((size_t)tapo * NPOS + posn) * 2) = pk;
            }
        }
    }
}

// ---------------------------------------------------------------------------
// sample_einsum v9: LDS-slab gathers (DS pipe) with global fallback.
// Block = 1 wave (64 thr = 16 wcol x 4 ch-octets), 16 outputs/block,
// grid 8192 = 32d x 64h x 4 xseg. Slab = xT[z in d-2..d+2][y in h-2..h+2]
// [x in xb-2..xb+17] staged to 32 KB LDS (5 blocks/CU). Corners inside the
// slab (essentially all: offset std ~0.3) are ds_read_b128 — off the TA
// pipe, which r6/r8 showed is the wall at ~50+ cy per scattered gather.
// Out-of-slab corners fall back to the exact r8 global gather (exec-masked,
// near-never taken) — bitwise-identical results either path.
// ---------------------------------------------------------------------------
__global__ __launch_bounds__(64) void sample_einsum(
    const unsigned short* __restrict__ xT,
    const unsigned short* __restrict__ wAe,
    const unsigned int* __restrict__ offmH,
    const float* __restrict__ bias, float* __restrict__ out)
{
    __shared__ __align__(16) unsigned short sX[SLAB_POS * 32];   // 32,000 B

    int bid = blockIdx.x;
    int swz = (bid & 7) * 1024 + (bid >> 3);       // 8 XCD chunks of 1024
    const int lane = threadIdx.x;                  // 64 threads = 1 wave
    const int wl = lane & 15, q = lane >> 4;
    const int seg = swz & 3;
    const int rowid = swz >> 2;                    // (d,h) row
    const int d = rowid >> 6, h = rowid & 63;
    const int xb = seg * 16;
    const int wcol = xb + wl;
    const int pos = rowid * WW + wcol;
    const int zlo = d - 2, ylo = h - 2, xlo = xb - 2;

    // ---- stage slab: 500 pos x 4 sectors = 2000 x 16B chunks, coalesced ----
    for (int c = lane; c < SLAB_POS * 4; c += 64) {
        int p = c >> 2, s = c & 3;
        int pz = p / (SLAB_Y * SLAB_X);
        int rem = p - pz * (SLAB_Y * SLAB_X);
        int py = rem / SLAB_X;
        int px = rem - py * SLAB_X;
        int z = zlo + pz, y = ylo + py, x = xlo + px;
        if (((unsigned)z < (unsigned)DD) & ((unsigned)y < (unsigned)HH) &
            ((unsigned)x < (unsigned)WW)) {
            uint4v v = *(const uint4v*)(xT + ((size_t)((z * HH + y) * WW + x)) * 32 + s * 8);
            *(uint4v*)(sX + (size_t)p * 32 + s * 8) = v;
        }
    }
    __syncthreads();   // single wave: compiles to waitcnt; orders stage->read

    const unsigned short* xTq  = xT + q * 8;
    const unsigned short* wAeL = wAe + (size_t)lane * 8;
    float4v accA0 = (float4v){0.f, 0.f, 0.f, 0.f};
    float4v accA1 = (float4v){0.f, 0.f, 0.f, 0.f};
    float4v accB0 = (float4v){0.f, 0.f, 0.f, 0.f};
    float4v accB1 = (float4v){0.f, 0.f, 0.f, 0.f};

    // prefetch offm for tap 0
    uint2v omc = *(const uint2v*)(offmH + (size_t)pos * 2);

    for (int kz = 0; kz < 3; kz++) {
        float zbase = (float)(d + kz - 1);
#pragma unroll
        for (int j = 0; j < 9; j++) {
            const int ky = j / 3, kx = j % 3;      // compile-time
            int tap = kz * 9 + j;

            int tapn = min(tap + 1, 26);
            uint2v omn = *(const uint2v*)(offmH + ((size_t)tapn * NPOS + pos) * 2);

            float zc = zbase + h2f((unsigned short)(omc.x & 0xFFFF));
            float yc = (float)(h + ky - 1) + h2f((unsigned short)(omc.x >> 16));
            float xc = (float)(wcol + kx - 1) + h2f((unsigned short)(omc.y & 0xFFFF));
            float m  = h2f((unsigned short)(omc.y >> 16));

            float zf = floorf(zc), yf = floorf(yc), xf = floorf(xc);
            int z0 = (int)zf, y0 = (int)yf, x0 = (int)xf;
            float fz = zc - zf, fy = yc - yf, fx = xc - xf;

            float wz0 = (z0 >= 0 && z0 < DD)         ? (1.f - fz) : 0.f;
            float wz1 = (z0 + 1 >= 0 && z0 + 1 < DD) ? fz         : 0.f;
            float wy0 = (y0 >= 0 && y0 < HH)         ? (1.f - fy) : 0.f;
            float wy1 = (y0 + 1 >= 0 && y0 + 1 < HH) ? fy         : 0.f;
            float wx0 = (x0 >= 0 && x0 < WW)         ? (1.f - fx) : 0.f;
            float wx1 = (x0 + 1 >= 0 && x0 + 1 < WW) ? fx         : 0.f;

            float mz0 = m * wz0, mz1 = m * wz1;
            float a00 = mz0 * wy0, a01 = mz0 * wy1, a10 = mz1 * wy0, a11 = mz1 * wy1;
            float cw[8];
            cw[0] = a00 * wx0; cw[1] = a00 * wx1; cw[2] = a01 * wx0; cw[3] = a01 * wx1;
            cw[4] = a10 * wx0; cw[5] = a10 * wx1; cw[6] = a11 * wx0; cw[7] = a11 * wx1;

            int iz0 = min(max(z0, 0), DD - 1), iz1 = min(max(z0 + 1, 0), DD - 1);
            int iy0 = min(max(y0, 0), HH - 1), iy1 = min(max(y0 + 1, 0), HH - 1);
            int ix0 = min(max(x0, 0), WW - 1), ix1 = min(max(x0 + 1, 0), WW - 1);

            int pz0 = iz0 - zlo, pz1 = iz1 - zlo;
            int py0 = iy0 - ylo, py1 = iy1 - ylo;
            int px0 = ix0 - xlo, px1 = ix1 - xlo;
            bool bz0 = (unsigned)pz0 < SLAB_Z, bz1 = (unsigned)pz1 < SLAB_Z;
            bool by0 = (unsigned)py0 < SLAB_Y, by1 = (unsigned)py1 < SLAB_Y;
            bool bx0 = (unsigned)px0 < SLAB_X, bx1 = (unsigned)px1 < SLAB_X;

            int g00 = (iz0 * HH + iy0) * WW, g01 = (iz0 * HH + iy1) * WW;
            int g10 = (iz1 * HH + iy0) * WW, g11 = (iz1 * HH + iy1) * WW;

            short8 cnr[8];
#define FETCH(idx, BZ, BY, BX, PZ, PY, PX, GOFF)                            \
            if (BZ & BY & BX) {                                             \
                int lp = ((PZ) * SLAB_Y + (PY)) * SLAB_X + (PX);            \
                cnr[idx] = *(const short8*)(sX + (size_t)lp * 32 + q * 8);  \
            } else {                                                        \
                cnr[idx] = *(const short8*)(xTq + (size_t)(GOFF) * 32);     \
            }
            FETCH(0, bz0, by0, bx0, pz0, py0, px0, g00 + ix0)
            FETCH(1, bz0, by0, bx1, pz0, py0, px1, g00 + ix1)
            FETCH(2, bz0, by1, bx0, pz0, py1, px0, g01 + ix0)
            FETCH(3, bz0, by1, bx1, pz0, py1, px1, g01 + ix1)
            FETCH(4, bz1, by0, bx0, pz1, py0, px0, g10 + ix0)
            FETCH(5, bz1, by0, bx1, pz1, py0, px1, g10 + ix1)
            FETCH(6, bz1, by1, bx0, pz1, py1, px0, g11 + ix0)
            FETCH(7, bz1, by1, bx1, pz1, py1, px1, g11 + ix1)
#undef FETCH

            const unsigned short* aep = wAeL + (size_t)tap * 1024;
            half8 a0 = __builtin_bit_cast(half8, *(const short8*)(aep));
            half8 a1 = __builtin_bit_cast(half8, *(const short8*)(aep + 512));

#pragma unroll
            for (int c = 0; c < 8; c++) {
                _Float16 ch = (_Float16)cw[c];
                half8 bh = __builtin_bit_cast(half8, cnr[c]) * ch;   // 4x v_pk_mul_f16
                if (c < 4) {
                    accA0 = mfma16(a0, bh, accA0);
                    accA1 = mfma16(a1, bh, accA1);
                } else {
                    accB0 = mfma16(a0, bh, accB0);
                    accB1 = mfma16(a1, bh, accB1);
                }
            }

            omc = omn;
        }
    }

    // epilogue: merge accumulator banks; C/D layout col = lane&15, row = q*4+r
    int sp = pos;
#pragma unroll
    for (int r = 0; r < 4; r++) {
        int co0 = q * 4 + r;
        out[co0 * CSTRIDE + sp]        = accA0[r] + accB0[r] + bias[co0];
        out[(16 + co0) * CSTRIDE + sp] = accA1[r] + accB1[r] + bias[16 + co0];
    }
}

// ---------------------------------------------------------------------------
extern "C" void kernel_launch(void* const* d_in, const int* in_sizes, int n_in,
                              void* d_out, int out_size, void* d_ws, size_t ws_size,
                              hipStream_t stream) {
    const float* x      = (const float*)d_in[0];
    const float* w_off  = (const float*)d_in[1];
    const float* b_off  = (const float*)d_in[2];
    const float* w_mask = (const float*)d_in[3];
    const float* b_mask = (const float*)d_in[4];
    const float* w      = (const float*)d_in[5];
    const float* b      = (const float*)d_in[6];
    float* out = (float*)d_out;

    // workspace layout (16B aligned, ~37.0 MB total):
    //   xT    8,388,608 B   fp16 x[pos][32ch]
    //   wAc     193,536 B   conv A-frags (fp16)
    //   wAe      55,296 B   einsum A-frags (fp16)
    //   offmH 28,311,552 B  fp16x4 {oz,oy,ox,mask}[tap][pos]
    unsigned short* xT  = (unsigned short*)d_ws;
    unsigned short* wAc = xT + (size_t)NPOS * 32;
    unsigned short* wAe = wAc + 27 * 7 * 64 * 8;
    unsigned int* offmH = (unsigned int*)(wAe + 27 * 2 * 64 * 8);

    hipLaunchKernelGGL(prep_all, dim3(NPOS / 256 + 486), dim3(256), 0, stream,
                       x, xT, w_off, w_mask, w, wAc, wAe);
    hipLaunchKernelGGL(conv_offm, dim3(1024), dim3(256), 0, stream,
                       xT, wAc, b_off, b_mask, offmH);
    hipLaunchKernelGGL(sample_einsum, dim3(8192), dim3(64), 0, stream,
                       xT, wAe, offmH, b, out);
}

// Round 11
// 226.325 us; speedup vs baseline: 1.5087x; 1.5087x over previous
//
#include <hip/hip_runtime.h>
#include <math.h>

// Problem constants: B=1, CIN=COUT=32, KS=3 (K=27), D=32, H=W=64, stride=1, pad=1, dil=1
#define DD 32
#define HH 64
#define WW 64
#define CSTRIDE (DD * HH * WW)   // 131072
#define NPOS (DD * HH * WW)
#define SECSZ (NPOS * 8)         // shorts per channel-octet sector of xT

// sample_einsum slab: block covers 4 d-rows x 1 h x 16 x. Slab spans
// z in d0-2..d0+5, y in h-2..h+2, x in xb-2..xb+17.
#define SLAB_Z 8
#define SLAB_Y 5
#define SLAB_X 20
#define SLAB_POS (SLAB_Z * SLAB_Y * SLAB_X)   // 800 positions
// LDS layout: sector-major sX[q][p][8 shorts] -> 8-lane groups with
// consecutive p read 128 contiguous bytes = all 32 banks, conflict-free
// (r9's [pos][sector] layout was an 8-way conflict: banks {q*4, q*4+16}).
#define SLAB_SEC (SLAB_POS * 8)               // shorts per LDS sector (12,800 B)

typedef __attribute__((ext_vector_type(8))) short  short8;      // 16B load vehicle
typedef _Float16 __attribute__((ext_vector_type(8))) half8;     // 8 fp16 MFMA A/B frag
typedef __attribute__((ext_vector_type(4))) float  float4v;     // MFMA C/D frag
typedef __attribute__((ext_vector_type(2))) float  f2v;
typedef __attribute__((ext_vector_type(4))) unsigned int uint4v;
typedef __attribute__((ext_vector_type(2))) unsigned int uint2v;

__device__ __forceinline__ unsigned short f2h(float f) {
    return __builtin_bit_cast(unsigned short, (_Float16)f);
}
__device__ __forceinline__ float h2f(unsigned short u) {
    return (float)__builtin_bit_cast(_Float16, u);
}
__device__ __forceinline__ unsigned pkh(float a, float b) {
    return (unsigned)f2h(a) | ((unsigned)f2h(b) << 16);
}
__device__ __forceinline__ float4v mfma16(half8 a, half8 b, float4v c) {
    return __builtin_amdgcn_mfma_f32_16x16x32_f16(a, b, c, 0, 0, 0);
}

// ---------------------------------------------------------------------------
// prep_all: fused prep_x + prep_w. xT is SECTOR-MAJOR:
//   xT[q][pos][8ch] (q = channel octet). Writes remain coalesced (4 streams).
// ---------------------------------------------------------------------------
__global__ __launch_bounds__(256) void prep_all(
    const float* __restrict__ x, unsigned short* __restrict__ xT,
    const float* __restrict__ w_off, const float* __restrict__ w_mask,
    const float* __restrict__ w,
    unsigned short* __restrict__ wAc, unsigned short* __restrict__ wAe)
{
    if (blockIdx.x < NPOS / 256) {
        int pos = blockIdx.x * 256 + threadIdx.x;
        float v[32];
#pragma unroll
        for (int ci = 0; ci < 32; ci++) v[ci] = x[ci * CSTRIDE + pos];
        unsigned dw[16];
#pragma unroll
        for (int p = 0; p < 16; p++)
            dw[p] = (unsigned)f2h(v[2 * p]) | ((unsigned)f2h(v[2 * p + 1]) << 16);
#pragma unroll
        for (int o = 0; o < 4; o++) {
            uint4v t4 = {dw[4 * o], dw[4 * o + 1], dw[4 * o + 2], dw[4 * o + 3]};
            *(uint4v*)(xT + (size_t)o * SECSZ + (size_t)pos * 8) = t4;
        }
    } else {
        int i = (blockIdx.x - NPOS / 256) * 256 + threadIdx.x;
        if (i < 27 * 7 * 64 * 8) {                       // 96768: conv A-frags
            int j    = i & 7;
            int lane = (i >> 3) & 63;
            int fm   = i >> 9;
            int mt   = fm % 7;
            int tapw = fm / 7;                           // conv kernel tap
            int ch   = mt * 16 + (lane & 15);            // ch' = tap_o*4+comp
            int ci   = (lane >> 4) * 8 + j;
            float v = 0.f;
            if (ch < 108) {
                int tapo = ch >> 2, comp = ch & 3;
                v = (comp < 3) ? w_off[((comp * 27 + tapo) * 32 + ci) * 27 + tapw]
                               : w_mask[(tapo * 32 + ci) * 27 + tapw];
            }
            wAc[i] = f2h(v);
        } else {                                         // 27648: einsum A-frags
            int i2   = i - 27 * 7 * 64 * 8;
            int j    = i2 & 7;
            int lane = (i2 >> 3) & 63;
            int fm   = i2 >> 9;
            int mt   = fm % 2;
            int tapw = fm / 2;
            int co   = mt * 16 + (lane & 15);
            int ci   = (lane >> 4) * 8 + j;
            wAe[i2] = f2h(w[(co * 32 + ci) * 27 + tapw]);
        }
    }
}

// ---------------------------------------------------------------------------
// conv_offm v7b (r8 passing version), adapted to sector-major xT.
// ---------------------------------------------------------------------------
__global__ __launch_bounds__(256, 4) void conv_offm(
    const unsigned short* __restrict__ xT,
    const unsigned short* __restrict__ wAc,
    const float* __restrict__ b_off, const float* __restrict__ b_mask,
    unsigned int* __restrict__ offmH)
{
    __shared__ __align__(16) unsigned short sA[2][3584];   // 2 x 7168 B

    int bid = blockIdx.x;
    int swz = (bid & 7) * 128 + (bid >> 3);        // 8 XCD chunks of 128
    const int t = threadIdx.x, lane = t & 63;
    const int wv = t >> 6, wl = lane & 15, q = lane >> 4;
    const int row = swz * 2 + (wv >> 1);
    const int z = row >> 6, y = row & 63;
    const int xb = (wv & 1) * 32;
    const unsigned short* xTq = xT + (size_t)q * SECSZ;

    {
        uint4v v0a = *(const uint4v*)(wAc + (size_t)t * 8);
        uint4v v1a = *(const uint4v*)(wAc + 3584 + (size_t)t * 8);
        uint4v v0b, v1b;
        if (t < 192) {
            v0b = *(const uint4v*)(wAc + (size_t)(256 + t) * 8);
            v1b = *(const uint4v*)(wAc + 3584 + (size_t)(256 + t) * 8);
        }
        *(uint4v*)(&sA[0][0] + t * 8) = v0a;
        *(uint4v*)(&sA[1][0] + t * 8) = v1a;
        if (t < 192) {
            *(uint4v*)(&sA[0][0] + (256 + t) * 8) = v0b;
            *(uint4v*)(&sA[1][0] + (256 + t) * 8) = v1b;
        }
    }
    __syncthreads();

    float4v acc[7][2];
#pragma unroll
    for (int mt = 0; mt < 7; mt++)
#pragma unroll
        for (int nt = 0; nt < 2; nt++)
            acc[mt][nt] = (float4v){0.f, 0.f, 0.f, 0.f};

    for (int tap = 0; tap < 27; tap++) {
        const int p  = tap & 1;
        const int kz = tap / 9, r9 = tap - kz * 9;
        const int ky = r9 / 3,  kx = r9 - ky * 3;

        int zs = z + kz - 1;
        bool zok = (unsigned)zs < (unsigned)DD;
        int zc = min(max(zs, 0), DD - 1);
        int ys = y + ky - 1;
        bool yok = (unsigned)ys < (unsigned)HH;
        int yc = min(max(ys, 0), HH - 1);
        int rowp = (zc * HH + yc) * WW;

        short8 b0, b1;
#pragma unroll
        for (int nt = 0; nt < 2; nt++) {
            int xs = xb + nt * 16 + wl + kx - 1;
            bool ok = zok & yok & ((unsigned)xs < (unsigned)WW);
            int xc = min(max(xs, 0), WW - 1);
            short8 bb = *(const short8*)(xTq + (size_t)(rowp + xc) * 8);
            if (!ok) bb = (short8)0;
            if (nt == 0) b0 = bb; else b1 = bb;
        }

        uint4v sva, svb;
        bool pre = (tap + 2 < 27);
        if (pre) {
            const unsigned short* src = wAc + (size_t)(tap + 2) * 3584;
            sva = *(const uint4v*)(src + (size_t)t * 8);
            if (t < 192) svb = *(const uint4v*)(src + (size_t)(256 + t) * 8);
        }

        const unsigned short* sAp = &sA[p][0] + lane * 8;
#pragma unroll
        for (int mt = 0; mt < 7; mt++) {
            half8 a = __builtin_bit_cast(half8, *(const short8*)(sAp + mt * 512));
            acc[mt][0] = mfma16(a, __builtin_bit_cast(half8, b0), acc[mt][0]);
            acc[mt][1] = mfma16(a, __builtin_bit_cast(half8, b1), acc[mt][1]);
        }

        __syncthreads();
        if (pre) {
            *(uint4v*)(&sA[p][0] + t * 8) = sva;
            if (t < 192) *(uint4v*)(&sA[p][0] + (256 + t) * 8) = svb;
        }
    }

    const int rowpos = row * WW;
#pragma unroll
    for (int mt = 0; mt < 7; mt++) {
        int tapo = mt * 4 + q;
        if (tapo < 27) {
            float bz = b_off[tapo], by = b_off[27 + tapo], bx = b_off[54 + tapo];
            float bm = b_mask[tapo];
#pragma unroll
            for (int nt = 0; nt < 2; nt++) {
                float4v v = acc[mt][nt];
                float mm = v.w + bm;
                mm = 1.f / (1.f + __expf(-mm));
                int posn = rowpos + xb + nt * 16 + wl;
                uint2v pk = { pkh(v.x + bz, v.y + by), pkh(v.z + bx, mm) };
                *(uint2v*)(offmH + ((size_t)tapo * NPOS + posn) * 2) = pk;
            }
        }
    }
}

// ---------------------------------------------------------------------------
// sample_einsum v10: sector-major LDS slab, 4-wave z-stacked blocks.
// Block = 256 thr = 4 waves; wave wv handles row (d0+wv, h), 16 x-cols.
// Shared slab: z in d0-2..d0+5, y in h-2..h+2, x in xb-2..xb+17 (800 pos,
// 51.2 KB) -> 3 blocks/CU = 12 waves/CU. All slab reads conflict-free by
// layout; out-of-slab corners (rare) fall back to global gather.
// ---------------------------------------------------------------------------
__global__ __launch_bounds__(256, 3) void sample_einsum(
    const unsigned short* __restrict__ xT,
    const unsigned short* __restrict__ wAe,
    const unsigned int* __restrict__ offmH,
    const float* __restrict__ bias, float* __restrict__ out)
{
    __shared__ __align__(16) unsigned short sX[4 * SLAB_SEC];   // 51,200 B

    int bid = blockIdx.x;                          // grid = 2048
    int swz = (bid & 7) * 256 + (bid >> 3);        // 8 XCD chunks of 256
    const int t = threadIdx.x, lane = t & 63;
    const int wv = t >> 6, wl = lane & 15, q = lane >> 4;
    const int seg = swz & 3;
    const int rowid = swz >> 2;                    // 0..511
    const int h  = rowid & 63;
    const int d0 = (rowid >> 6) * 4;
    const int d  = d0 + wv;
    const int xb = seg * 16;
    const int wcol = xb + wl;
    const int pos = (d * HH + h) * WW + wcol;
    const int zlo = d0 - 2, ylo = h - 2, xlo = xb - 2;

    // prefetch offm for tap 0 (overlaps staging)
    uint2v omc = *(const uint2v*)(offmH + (size_t)pos * 2);

    // ---- stage slab: per sector s, consecutive threads handle consecutive
    // slab positions -> contiguous global reads AND contiguous LDS writes ----
    for (int c = t; c < SLAB_POS * 4; c += 256) {
        int s = c / SLAB_POS, p = c - s * SLAB_POS;
        int pz = p / (SLAB_Y * SLAB_X);
        int rem = p - pz * (SLAB_Y * SLAB_X);
        int py = rem / SLAB_X;
        int px = rem - py * SLAB_X;
        int z = zlo + pz, y = ylo + py, x = xlo + px;
        if (((unsigned)z < (unsigned)DD) & ((unsigned)y < (unsigned)HH) &
            ((unsigned)x < (unsigned)WW)) {
            uint4v v = *(const uint4v*)(xT + (size_t)s * SECSZ +
                                        ((size_t)((z * HH + y) * WW + x)) * 8);
            *(uint4v*)(sX + (size_t)s * SLAB_SEC + (size_t)p * 8) = v;
        }
    }
    __syncthreads();

    const unsigned short* xTq  = xT + (size_t)q * SECSZ;
    const unsigned short* sXq  = sX + (size_t)q * SLAB_SEC;
    const unsigned short* wAeL = wAe + (size_t)lane * 8;
    float4v accA0 = (float4v){0.f, 0.f, 0.f, 0.f};
    float4v accA1 = (float4v){0.f, 0.f, 0.f, 0.f};
    float4v accB0 = (float4v){0.f, 0.f, 0.f, 0.f};
    float4v accB1 = (float4v){0.f, 0.f, 0.f, 0.f};

    for (int kz = 0; kz < 3; kz++) {
        float zbase = (float)(d + kz - 1);
#pragma unroll
        for (int j = 0; j < 9; j++) {
            const int ky = j / 3, kx = j % 3;      // compile-time
            int tap = kz * 9 + j;

            int tapn = min(tap + 1, 26);
            uint2v omn = *(const uint2v*)(offmH + ((size_t)tapn * NPOS + pos) * 2);

            float zc = zbase + h2f((unsigned short)(omc.x & 0xFFFF));
            float yc = (float)(h + ky - 1) + h2f((unsigned short)(omc.x >> 16));
            float xc = (float)(wcol + kx - 1) + h2f((unsigned short)(omc.y & 0xFFFF));
            float m  = h2f((unsigned short)(omc.y >> 16));

            float zf = floorf(zc), yf = floorf(yc), xf = floorf(xc);
            int z0 = (int)zf, y0 = (int)yf, x0 = (int)xf;
            float fz = zc - zf, fy = yc - yf, fx = xc - xf;

            float wz0 = (z0 >= 0 && z0 < DD)         ? (1.f - fz) : 0.f;
            float wz1 = (z0 + 1 >= 0 && z0 + 1 < DD) ? fz         : 0.f;
            float wy0 = (y0 >= 0 && y0 < HH)         ? (1.f - fy) : 0.f;
            float wy1 = (y0 + 1 >= 0 && y0 + 1 < HH) ? fy         : 0.f;
            float wx0 = (x0 >= 0 && x0 < WW)         ? (1.f - fx) : 0.f;
            float wx1 = (x0 + 1 >= 0 && x0 + 1 < WW) ? fx         : 0.f;

            float mz0 = m * wz0, mz1 = m * wz1;
            float a00 = mz0 * wy0, a01 = mz0 * wy1, a10 = mz1 * wy0, a11 = mz1 * wy1;
            float cw[8];
            cw[0] = a00 * wx0; cw[1] = a00 * wx1; cw[2] = a01 * wx0; cw[3] = a01 * wx1;
            cw[4] = a10 * wx0; cw[5] = a10 * wx1; cw[6] = a11 * wx0; cw[7] = a11 * wx1;

            int iz0 = min(max(z0, 0), DD - 1), iz1 = min(max(z0 + 1, 0), DD - 1);
            int iy0 = min(max(y0, 0), HH - 1), iy1 = min(max(y0 + 1, 0), HH - 1);
            int ix0 = min(max(x0, 0), WW - 1), ix1 = min(max(x0 + 1, 0), WW - 1);

            int pz0 = iz0 - zlo, pz1 = iz1 - zlo;
            int py0 = iy0 - ylo, py1 = iy1 - ylo;
            int px0 = ix0 - xlo, px1 = ix1 - xlo;
            bool bz0 = (unsigned)pz0 < SLAB_Z, bz1 = (unsigned)pz1 < SLAB_Z;
            bool by0 = (unsigned)py0 < SLAB_Y, by1 = (unsigned)py1 < SLAB_Y;
            bool bx0 = (unsigned)px0 < SLAB_X, bx1 = (unsigned)px1 < SLAB_X;

            int g00 = (iz0 * HH + iy0) * WW, g01 = (iz0 * HH + iy1) * WW;
            int g10 = (iz1 * HH + iy0) * WW, g11 = (iz1 * HH + iy1) * WW;

            short8 cnr[8];
#define FETCH(idx, BZ, BY, BX, PZ, PY, PX, GOFF)                              \
            if (BZ & BY & BX) {                                               \
                int lp = ((PZ) * SLAB_Y + (PY)) * SLAB_X + (PX);              \
                cnr[idx] = *(const short8*)(sXq + (size_t)lp * 8);            \
            } else {                                                          \
                cnr[idx] = *(const short8*)(xTq + (size_t)(GOFF) * 8);        \
            }
            FETCH(0, bz0, by0, bx0, pz0, py0, px0, g00 + ix0)
            FETCH(1, bz0, by0, bx1, pz0, py0, px1, g00 + ix1)
            FETCH(2, bz0, by1, bx0, pz0, py1, px0, g01 + ix0)
            FETCH(3, bz0, by1, bx1, pz0, py1, px1, g01 + ix1)
            FETCH(4, bz1, by0, bx0, pz1, py0, px0, g10 + ix0)
            FETCH(5, bz1, by0, bx1, pz1, py0, px1, g10 + ix1)
            FETCH(6, bz1, by1, bx0, pz1, py1, px0, g11 + ix0)
            FETCH(7, bz1, by1, bx1, pz1, py1, px1, g11 + ix1)
#undef FETCH

            const unsigned short* aep = wAeL + (size_t)tap * 1024;
            half8 a0 = __builtin_bit_cast(half8, *(const short8*)(aep));
            half8 a1 = __builtin_bit_cast(half8, *(const short8*)(aep + 512));

#pragma unroll
            for (int c = 0; c < 8; c++) {
                _Float16 ch = (_Float16)cw[c];
                half8 bh = __builtin_bit_cast(half8, cnr[c]) * ch;   // 4x v_pk_mul_f16
                if (c < 4) {
                    accA0 = mfma16(a0, bh, accA0);
                    accA1 = mfma16(a1, bh, accA1);
                } else {
                    accB0 = mfma16(a0, bh, accB0);
                    accB1 = mfma16(a1, bh, accB1);
                }
            }

            omc = omn;
        }
    }

    // epilogue: merge accumulator banks; C/D layout col = lane&15, row = q*4+r
    int sp = pos;
#pragma unroll
    for (int r = 0; r < 4; r++) {
        int co0 = q * 4 + r;
        out[co0 * CSTRIDE + sp]        = accA0[r] + accB0[r] + bias[co0];
        out[(16 + co0) * CSTRIDE + sp] = accA1[r] + accB1[r] + bias[16 + co0];
    }
}

// ---------------------------------------------------------------------------
extern "C" void kernel_launch(void* const* d_in, const int* in_sizes, int n_in,
                              void* d_out, int out_size, void* d_ws, size_t ws_size,
                              hipStream_t stream) {
    const float* x      = (const float*)d_in[0];
    const float* w_off  = (const float*)d_in[1];
    const float* b_off  = (const float*)d_in[2];
    const float* w_mask = (const float*)d_in[3];
    const float* b_mask = (const float*)d_in[4];
    const float* w      = (const float*)d_in[5];
    const float* b      = (const float*)d_in[6];
    float* out = (float*)d_out;

    // workspace layout (16B aligned, ~37.0 MB total):
    //   xT    8,388,608 B   fp16 x[4 sectors][pos][8ch]  (sector-major)
    //   wAc     193,536 B   conv A-frags (fp16)
    //   wAe      55,296 B   einsum A-frags (fp16)
    //   offmH 28,311,552 B  fp16x4 {oz,oy,ox,mask}[tap][pos]
    unsigned short* xT  = (unsigned short*)d_ws;
    unsigned short* wAc = xT + (size_t)NPOS * 32;
    unsigned short* wAe = wAc + 27 * 7 * 64 * 8;
    unsigned int* offmH = (unsigned int*)(wAe + 27 * 2 * 64 * 8);

    hipLaunchKernelGGL(prep_all, dim3(NPOS / 256 + 486), dim3(256), 0, stream,
                       x, xT, w_off, w_mask, w, wAc, wAe);
    hipLaunchKernelGGL(conv_offm, dim3(1024), dim3(256), 0, stream,
                       xT, wAc, b_off, b_mask, offmH);
    hipLaunchKernelGGL(sample_einsum, dim3(2048), dim3(256), 0, stream,
                       xT, wAe, offmH, b, out);
}

// Round 13
// 209.128 us; speedup vs baseline: 1.6327x; 1.0822x over previous
//
#include <hip/hip_runtime.h>
#include <math.h>

// Problem constants: B=1, CIN=COUT=32, KS=3 (K=27), D=32, H=W=64, stride=1, pad=1, dil=1
#define DD 32
#define HH 64
#define WW 64
#define CSTRIDE (DD * HH * WW)   // 131072
#define NPOS (DD * HH * WW)
#define SECSZ (NPOS * 8)         // shorts per channel-octet sector of xT

// sample_einsum slab: block covers 4 d-rows x 1 h x 16 x. Slab spans
// z in d0-2..d0+5, y in h-2..h+2, x in xb-2..xb+17.
#define SLAB_Z 8
#define SLAB_Y 5
#define SLAB_X 20
#define SLAB_POS (SLAB_Z * SLAB_Y * SLAB_X)   // 800 positions
// LDS layout: sector-major sX[q][p][8 shorts] -> 8-lane groups with
// consecutive p read 128 contiguous bytes = all 32 banks (r9's [pos][sector]
// layout was an 8-way conflict).
#define SLAB_SEC (SLAB_POS * 8)               // shorts per LDS sector (12,800 B)

typedef __attribute__((ext_vector_type(8))) short  short8;      // 16B load vehicle
typedef _Float16 __attribute__((ext_vector_type(8))) half8;     // 8 fp16 MFMA A/B frag
typedef __attribute__((ext_vector_type(4))) float  float4v;     // MFMA C/D frag
typedef __attribute__((ext_vector_type(2))) float  f2v;
typedef __attribute__((ext_vector_type(4))) unsigned int uint4v;
typedef __attribute__((ext_vector_type(2))) unsigned int uint2v;

__device__ __forceinline__ unsigned short f2h(float f) {
    return __builtin_bit_cast(unsigned short, (_Float16)f);
}
__device__ __forceinline__ float h2f(unsigned short u) {
    return (float)__builtin_bit_cast(_Float16, u);
}
__device__ __forceinline__ unsigned pkh(float a, float b) {
    return (unsigned)f2h(a) | ((unsigned)f2h(b) << 16);
}
__device__ __forceinline__ float4v mfma16(half8 a, half8 b, float4v c) {
    return __builtin_amdgcn_mfma_f32_16x16x32_f16(a, b, c, 0, 0, 0);
}

// ---------------------------------------------------------------------------
// prep_all: fused prep_x + prep_w. xT is SECTOR-MAJOR:
//   xT[q][pos][8ch] (q = channel octet). Writes remain coalesced (4 streams).
// (unchanged from r11)
// ---------------------------------------------------------------------------
__global__ __launch_bounds__(256) void prep_all(
    const float* __restrict__ x, unsigned short* __restrict__ xT,
    const float* __restrict__ w_off, const float* __restrict__ w_mask,
    const float* __restrict__ w,
    unsigned short* __restrict__ wAc, unsigned short* __restrict__ wAe)
{
    if (blockIdx.x < NPOS / 256) {
        int pos = blockIdx.x * 256 + threadIdx.x;
        float v[32];
#pragma unroll
        for (int ci = 0; ci < 32; ci++) v[ci] = x[ci * CSTRIDE + pos];
        unsigned dw[16];
#pragma unroll
        for (int p = 0; p < 16; p++)
            dw[p] = (unsigned)f2h(v[2 * p]) | ((unsigned)f2h(v[2 * p + 1]) << 16);
#pragma unroll
        for (int o = 0; o < 4; o++) {
            uint4v t4 = {dw[4 * o], dw[4 * o + 1], dw[4 * o + 2], dw[4 * o + 3]};
            *(uint4v*)(xT + (size_t)o * SECSZ + (size_t)pos * 8) = t4;
        }
    } else {
        int i = (blockIdx.x - NPOS / 256) * 256 + threadIdx.x;
        if (i < 27 * 7 * 64 * 8) {                       // 96768: conv A-frags
            int j    = i & 7;
            int lane = (i >> 3) & 63;
            int fm   = i >> 9;
            int mt   = fm % 7;
            int tapw = fm / 7;                           // conv kernel tap
            int ch   = mt * 16 + (lane & 15);            // ch' = tap_o*4+comp
            int ci   = (lane >> 4) * 8 + j;
            float v = 0.f;
            if (ch < 108) {
                int tapo = ch >> 2, comp = ch & 3;
                v = (comp < 3) ? w_off[((comp * 27 + tapo) * 32 + ci) * 27 + tapw]
                               : w_mask[(tapo * 32 + ci) * 27 + tapw];
            }
            wAc[i] = f2h(v);
        } else {                                         // 27648: einsum A-frags
            int i2   = i - 27 * 7 * 64 * 8;
            int j    = i2 & 7;
            int lane = (i2 >> 3) & 63;
            int fm   = i2 >> 9;
            int mt   = fm % 2;
            int tapw = fm / 2;
            int co   = mt * 16 + (lane & 15);
            int ci   = (lane >> 4) * 8 + j;
            wAe[i2] = f2h(w[(co * 32 + ci) * 27 + tapw]);
        }
    }
}

// ---------------------------------------------------------------------------
// conv_offm v7b (unchanged from r11).
// ---------------------------------------------------------------------------
__global__ __launch_bounds__(256, 4) void conv_offm(
    const unsigned short* __restrict__ xT,
    const unsigned short* __restrict__ wAc,
    const float* __restrict__ b_off, const float* __restrict__ b_mask,
    unsigned int* __restrict__ offmH)
{
    __shared__ __align__(16) unsigned short sA[2][3584];   // 2 x 7168 B

    int bid = blockIdx.x;
    int swz = (bid & 7) * 128 + (bid >> 3);        // 8 XCD chunks of 128
    const int t = threadIdx.x, lane = t & 63;
    const int wv = t >> 6, wl = lane & 15, q = lane >> 4;
    const int row = swz * 2 + (wv >> 1);
    const int z = row >> 6, y = row & 63;
    const int xb = (wv & 1) * 32;
    const unsigned short* xTq = xT + (size_t)q * SECSZ;

    {
        uint4v v0a = *(const uint4v*)(wAc + (size_t)t * 8);
        uint4v v1a = *(const uint4v*)(wAc + 3584 + (size_t)t * 8);
        uint4v v0b, v1b;
        if (t < 192) {
            v0b = *(const uint4v*)(wAc + (size_t)(256 + t) * 8);
            v1b = *(const uint4v*)(wAc + 3584 + (size_t)(256 + t) * 8);
        }
        *(uint4v*)(&sA[0][0] + t * 8) = v0a;
        *(uint4v*)(&sA[1][0] + t * 8) = v1a;
        if (t < 192) {
            *(uint4v*)(&sA[0][0] + (256 + t) * 8) = v0b;
            *(uint4v*)(&sA[1][0] + (256 + t) * 8) = v1b;
        }
    }
    __syncthreads();

    float4v acc[7][2];
#pragma unroll
    for (int mt = 0; mt < 7; mt++)
#pragma unroll
        for (int nt = 0; nt < 2; nt++)
            acc[mt][nt] = (float4v){0.f, 0.f, 0.f, 0.f};

    for (int tap = 0; tap < 27; tap++) {
        const int p  = tap & 1;
        const int kz = tap / 9, r9 = tap - kz * 9;
        const int ky = r9 / 3,  kx = r9 - ky * 3;

        int zs = z + kz - 1;
        bool zok = (unsigned)zs < (unsigned)DD;
        int zc = min(max(zs, 0), DD - 1);
        int ys = y + ky - 1;
        bool yok = (unsigned)ys < (unsigned)HH;
        int yc = min(max(ys, 0), HH - 1);
        int rowp = (zc * HH + yc) * WW;

        short8 b0, b1;
#pragma unroll
        for (int nt = 0; nt < 2; nt++) {
            int xs = xb + nt * 16 + wl + kx - 1;
            bool ok = zok & yok & ((unsigned)xs < (unsigned)WW);
            int xc = min(max(xs, 0), WW - 1);
            short8 bb = *(const short8*)(xTq + (size_t)(rowp + xc) * 8);
            if (!ok) bb = (short8)0;
            if (nt == 0) b0 = bb; else b1 = bb;
        }

        uint4v sva, svb;
        bool pre = (tap + 2 < 27);
        if (pre) {
            const unsigned short* src = wAc + (size_t)(tap + 2) * 3584;
            sva = *(const uint4v*)(src + (size_t)t * 8);
            if (t < 192) svb = *(const uint4v*)(src + (size_t)(256 + t) * 8);
        }

        const unsigned short* sAp = &sA[p][0] + lane * 8;
#pragma unroll
        for (int mt = 0; mt < 7; mt++) {
            half8 a = __builtin_bit_cast(half8, *(const short8*)(sAp + mt * 512));
            acc[mt][0] = mfma16(a, __builtin_bit_cast(half8, b0), acc[mt][0]);
            acc[mt][1] = mfma16(a, __builtin_bit_cast(half8, b1), acc[mt][1]);
        }

        __syncthreads();
        if (pre) {
            *(uint4v*)(&sA[p][0] + t * 8) = sva;
            if (t < 192) *(uint4v*)(&sA[p][0] + (256 + t) * 8) = svb;
        }
    }

    const int rowpos = row * WW;
#pragma unroll
    for (int mt = 0; mt < 7; mt++) {
        int tapo = mt * 4 + q;
        if (tapo < 27) {
            float bz = b_off[tapo], by = b_off[27 + tapo], bx = b_off[54 + tapo];
            float bm = b_mask[tapo];
#pragma unroll
            for (int nt = 0; nt < 2; nt++) {
                float4v v = acc[mt][nt];
                float mm = v.w + bm;
                mm = 1.f / (1.f + __expf(-mm));
                int posn = rowpos + xb + nt * 16 + wl;
                uint2v pk = { pkh(v.x + bz, v.y + by), pkh(v.z + bx, mm) };
                *(uint2v*)(offmH + ((size_t)tapo * NPOS + posn) * 2) = pk;
            }
        }
    }
}

// ---------------------------------------------------------------------------
// sample_einsum v13 = r11 (known-good defensive path, NO branch gating) with
// ONE change: the 8 weighted corners are combined in-register with packed
// fp16 FMAs (bh = sum_c cw[c]*cnr[c]; 4 pk_mul + 28 pk_fma = same 32 VALU
// ops as the old per-corner scaling) and fed to TWO MFMAs/tap instead of 16.
// r11's issue model: 165 VALU x 2cy + 16 MFMA x 5cy = 410 cy/wave-tap ->
// this cuts 14 MFMA x 5cy = -17%. Accumulator bank alternates on j-parity
// (compile-time) to break dependent-MFMA chains.
// ---------------------------------------------------------------------------
__global__ __launch_bounds__(256, 3) void sample_einsum(
    const unsigned short* __restrict__ xT,
    const unsigned short* __restrict__ wAe,
    const unsigned int* __restrict__ offmH,
    const float* __restrict__ bias, float* __restrict__ out)
{
    __shared__ __align__(16) unsigned short sX[4 * SLAB_SEC];   // 51,200 B

    int bid = blockIdx.x;                          // grid = 2048
    int swz = (bid & 7) * 256 + (bid >> 3);        // 8 XCD chunks of 256
    const int t = threadIdx.x, lane = t & 63;
    const int wv = t >> 6, wl = lane & 15, q = lane >> 4;
    const int seg = swz & 3;
    const int rowid = swz >> 2;                    // 0..511
    const int h  = rowid & 63;
    const int d0 = (rowid >> 6) * 4;
    const int d  = d0 + wv;
    const int xb = seg * 16;
    const int wcol = xb + wl;
    const int pos = (d * HH + h) * WW + wcol;
    const int zlo = d0 - 2, ylo = h - 2, xlo = xb - 2;

    // prefetch offm for tap 0 (overlaps staging)
    uint2v omc = *(const uint2v*)(offmH + (size_t)pos * 2);

    // ---- stage slab: per sector s, consecutive threads handle consecutive
    // slab positions -> contiguous global reads AND contiguous LDS writes ----
    for (int c = t; c < SLAB_POS * 4; c += 256) {
        int s = c / SLAB_POS, p = c - s * SLAB_POS;
        int pz = p / (SLAB_Y * SLAB_X);
        int rem = p - pz * (SLAB_Y * SLAB_X);
        int py = rem / SLAB_X;
        int px = rem - py * SLAB_X;
        int z = zlo + pz, y = ylo + py, x = xlo + px;
        if (((unsigned)z < (unsigned)DD) & ((unsigned)y < (unsigned)HH) &
            ((unsigned)x < (unsigned)WW)) {
            uint4v v = *(const uint4v*)(xT + (size_t)s * SECSZ +
                                        ((size_t)((z * HH + y) * WW + x)) * 8);
            *(uint4v*)(sX + (size_t)s * SLAB_SEC + (size_t)p * 8) = v;
        }
    }
    __syncthreads();

    const unsigned short* xTq  = xT + (size_t)q * SECSZ;
    const unsigned short* sXq  = sX + (size_t)q * SLAB_SEC;
    const unsigned short* wAeL = wAe + (size_t)lane * 8;
    float4v accA0 = (float4v){0.f, 0.f, 0.f, 0.f};
    float4v accA1 = (float4v){0.f, 0.f, 0.f, 0.f};
    float4v accB0 = (float4v){0.f, 0.f, 0.f, 0.f};
    float4v accB1 = (float4v){0.f, 0.f, 0.f, 0.f};

    for (int kz = 0; kz < 3; kz++) {
        float zbase = (float)(d + kz - 1);
#pragma unroll
        for (int j = 0; j < 9; j++) {
            const int ky = j / 3, kx = j % 3;      // compile-time
            int tap = kz * 9 + j;

            int tapn = min(tap + 1, 26);
            uint2v omn = *(const uint2v*)(offmH + ((size_t)tapn * NPOS + pos) * 2);

            float zc = zbase + h2f((unsigned short)(omc.x & 0xFFFF));
            float yc = (float)(h + ky - 1) + h2f((unsigned short)(omc.x >> 16));
            float xc = (float)(wcol + kx - 1) + h2f((unsigned short)(omc.y & 0xFFFF));
            float m  = h2f((unsigned short)(omc.y >> 16));

            float zf = floorf(zc), yf = floorf(yc), xf = floorf(xc);
            int z0 = (int)zf, y0 = (int)yf, x0 = (int)xf;
            float fz = zc - zf, fy = yc - yf, fx = xc - xf;

            float wz0 = (z0 >= 0 && z0 < DD)         ? (1.f - fz) : 0.f;
            float wz1 = (z0 + 1 >= 0 && z0 + 1 < DD) ? fz         : 0.f;
            float wy0 = (y0 >= 0 && y0 < HH)         ? (1.f - fy) : 0.f;
            float wy1 = (y0 + 1 >= 0 && y0 + 1 < HH) ? fy         : 0.f;
            float wx0 = (x0 >= 0 && x0 < WW)         ? (1.f - fx) : 0.f;
            float wx1 = (x0 + 1 >= 0 && x0 + 1 < WW) ? fx         : 0.f;

            float mz0 = m * wz0, mz1 = m * wz1;
            float a00 = mz0 * wy0, a01 = mz0 * wy1, a10 = mz1 * wy0, a11 = mz1 * wy1;
            float cw[8];
            cw[0] = a00 * wx0; cw[1] = a00 * wx1; cw[2] = a01 * wx0; cw[3] = a01 * wx1;
            cw[4] = a10 * wx0; cw[5] = a10 * wx1; cw[6] = a11 * wx0; cw[7] = a11 * wx1;

            int iz0 = min(max(z0, 0), DD - 1), iz1 = min(max(z0 + 1, 0), DD - 1);
            int iy0 = min(max(y0, 0), HH - 1), iy1 = min(max(y0 + 1, 0), HH - 1);
            int ix0 = min(max(x0, 0), WW - 1), ix1 = min(max(x0 + 1, 0), WW - 1);

            int pz0 = iz0 - zlo, pz1 = iz1 - zlo;
            int py0 = iy0 - ylo, py1 = iy1 - ylo;
            int px0 = ix0 - xlo, px1 = ix1 - xlo;
            bool bz0 = (unsigned)pz0 < SLAB_Z, bz1 = (unsigned)pz1 < SLAB_Z;
            bool by0 = (unsigned)py0 < SLAB_Y, by1 = (unsigned)py1 < SLAB_Y;
            bool bx0 = (unsigned)px0 < SLAB_X, bx1 = (unsigned)px1 < SLAB_X;

            int g00 = (iz0 * HH + iy0) * WW, g01 = (iz0 * HH + iy1) * WW;
            int g10 = (iz1 * HH + iy0) * WW, g11 = (iz1 * HH + iy1) * WW;

            short8 cnr[8];
#define FETCH(idx, BZ, BY, BX, PZ, PY, PX, GOFF)                              \
            if (BZ & BY & BX) {                                               \
                int lp = ((PZ) * SLAB_Y + (PY)) * SLAB_X + (PX);              \
                cnr[idx] = *(const short8*)(sXq + (size_t)lp * 8);            \
            } else {                                                          \
                cnr[idx] = *(const short8*)(xTq + (size_t)(GOFF) * 8);        \
            }
            FETCH(0, bz0, by0, bx0, pz0, py0, px0, g00 + ix0)
            FETCH(1, bz0, by0, bx1, pz0, py0, px1, g00 + ix1)
            FETCH(2, bz0, by1, bx0, pz0, py1, px0, g01 + ix0)
            FETCH(3, bz0, by1, bx1, pz0, py1, px1, g01 + ix1)
            FETCH(4, bz1, by0, bx0, pz1, py0, px0, g10 + ix0)
            FETCH(5, bz1, by0, bx1, pz1, py0, px1, g10 + ix1)
            FETCH(6, bz1, by1, bx0, pz1, py1, px0, g11 + ix0)
            FETCH(7, bz1, by1, bx1, pz1, py1, px1, g11 + ix1)
#undef FETCH

            // fp16 interpolation chain: bh = sum_c cw[c]*cnr[c]
            // (4 pk_mul + 28 pk_fma — same VALU count as old per-corner
            //  scaling, but feeds 2 MFMAs instead of 16)
            half8 bh = __builtin_bit_cast(half8, cnr[0]) * (_Float16)cw[0];
#pragma unroll
            for (int c = 1; c < 8; c++)
                bh = __builtin_bit_cast(half8, cnr[c]) * (_Float16)cw[c] + bh;

            const unsigned short* aep = wAeL + (size_t)tap * 1024;
            half8 a0 = __builtin_bit_cast(half8, *(const short8*)(aep));
            half8 a1 = __builtin_bit_cast(half8, *(const short8*)(aep + 512));

            if (j & 1) {              // compile-time parity: break MFMA chains
                accB0 = mfma16(a0, bh, accB0);
                accB1 = mfma16(a1, bh, accB1);
            } else {
                accA0 = mfma16(a0, bh, accA0);
                accA1 = mfma16(a1, bh, accA1);
            }

            omc = omn;
        }
    }

    // epilogue: merge accumulator banks; C/D layout col = lane&15, row = q*4+r
    int sp = pos;
#pragma unroll
    for (int r = 0; r < 4; r++) {
        int co0 = q * 4 + r;
        out[co0 * CSTRIDE + sp]        = accA0[r] + accB0[r] + bias[co0];
        out[(16 + co0) * CSTRIDE + sp] = accA1[r] + accB1[r] + bias[16 + co0];
    }
}

// ---------------------------------------------------------------------------
extern "C" void kernel_launch(void* const* d_in, const int* in_sizes, int n_in,
                              void* d_out, int out_size, void* d_ws, size_t ws_size,
                              hipStream_t stream) {
    const float* x      = (const float*)d_in[0];
    const float* w_off  = (const float*)d_in[1];
    const float* b_off  = (const float*)d_in[2];
    const float* w_mask = (const float*)d_in[3];
    const float* b_mask = (const float*)d_in[4];
    const float* w      = (const float*)d_in[5];
    const float* b      = (const float*)d_in[6];
    float* out = (float*)d_out;

    // workspace layout (16B aligned, ~37.0 MB total):
    //   xT    8,388,608 B   fp16 x[4 sectors][pos][8ch]  (sector-major)
    //   wAc     193,536 B   conv A-frags (fp16)
    //   wAe      55,296 B   einsum A-frags (fp16)
    //   offmH 28,311,552 B  fp16x4 {oz,oy,ox,mask}[tap][pos]
    unsigned short* xT  = (unsigned short*)d_ws;
    unsigned short* wAc = xT + (size_t)NPOS * 32;
    unsigned short* wAe = wAc + 27 * 7 * 64 * 8;
    unsigned int* offmH = (unsigned int*)(wAe + 27 * 2 * 64 * 8);

    hipLaunchKernelGGL(prep_all, dim3(NPOS / 256 + 486), dim3(256), 0, stream,
                       x, xT, w_off, w_mask, w, wAc, wAe);
    hipLaunchKernelGGL(conv_offm, dim3(1024), dim3(256), 0, stream,
                       xT, wAc, b_off, b_mask, offmH);
    hipLaunchKernelGGL(sample_einsum, dim3(2048), dim3(256), 0, stream,
                       xT, wAe, offmH, b, out);
}